// Round 2
// baseline (289.273 us; speedup 1.0000x reference)
//
#include <hip/hip_runtime.h>
#include <hip/hip_bf16.h>

#define M_DIM 4096
#define N_DIM 4096
#define K_DIM 4096
#define BM 128
#define BN 128
#define BK 32
#define NT (K_DIM / BK)
#define LDS_STRIDE 40  // fallback kernel only

typedef __attribute__((ext_vector_type(8))) short short8;
typedef __attribute__((ext_vector_type(4))) float float4v;

__device__ __forceinline__ unsigned short f2bf(float f) {
    return __builtin_bit_cast(unsigned short, __float2bfloat16(f));
}

// async global->LDS, 16B per lane. LDS dest is wave-uniform base + lane*16 (HW).
__device__ __forceinline__ void gload_lds16(const unsigned short* gsrc, unsigned short* lds) {
    __builtin_amdgcn_global_load_lds(
        (const __attribute__((address_space(1))) unsigned int*)gsrc,
        (__attribute__((address_space(3))) unsigned int*)lds,
        16, 0, 0);
}

// ---------------- fp32 -> bf16 conversion pass ----------------
__global__ __launch_bounds__(256)
void cvt_fp32_bf16(const float* __restrict__ X, const float* __restrict__ W,
                   unsigned short* __restrict__ XB, unsigned short* __restrict__ WB) {
    const long per_mat = (long)M_DIM * K_DIM / 8;  // vec8 units per matrix
    const long total   = 2 * per_mat;
    for (long u = (long)blockIdx.x * blockDim.x + threadIdx.x; u < total;
         u += (long)gridDim.x * blockDim.x) {
        const float* src;
        unsigned short* dst;
        long v;
        if (u < per_mat) { src = X; dst = XB; v = u; }
        else             { src = W; dst = WB; v = u - per_mat; }
        float4v a = *(const float4v*)(src + v * 8);
        float4v b = *(const float4v*)(src + v * 8 + 4);
        short8 o;
#pragma unroll
        for (int e = 0; e < 4; ++e) {
            o[e]     = (short)f2bf(a[e]);
            o[e + 4] = (short)f2bf(b[e]);
        }
        *(short8*)(dst + v * 8) = o;
    }
}

// ---------------- bf16 GEMM, global_load_lds, fragment-major LDS ----------------
// LDS A buffer = 8 chunks of [64 lanes][8 bf16]; chunk c holds fragment
// rows (c>>2)*64 + (c&3)*16 + (lane&15), k-cols (lane>>4)*8 .. +8.
// ds_read_b128 at base + lane*16 -> conflict-free; no ds_writes at all.
__global__ __launch_bounds__(256, 2)
void gemm_bf16(const unsigned short* __restrict__ XB, const unsigned short* __restrict__ WB,
               const float* __restrict__ Bv, float* __restrict__ O) {
    __shared__ __align__(16) unsigned short lds_a[2][BM * BK];
    __shared__ __align__(16) unsigned short lds_b[2][BN * BK];

    const int tid  = threadIdx.x;
    const int lane = tid & 63;
    const int wid  = tid >> 6;
    const int wr   = wid >> 1;
    const int wc   = wid & 1;
    const int brow = blockIdx.y * BM;
    const int bcol = blockIdx.x * BN;

    // wave `wid` stages chunks {2*wid, 2*wid+1} of both A and B
    const int klane = (lane >> 4) * 8;
    int rA[2];
#pragma unroll
    for (int j = 0; j < 2; ++j) {
        const int c = wid * 2 + j;
        rA[j] = (c >> 2) * 64 + (c & 3) * 16 + (lane & 15);
    }

    auto stage = [&](int buf, int kt) {
        const long kofs = (long)kt * BK + klane;
#pragma unroll
        for (int j = 0; j < 2; ++j) {
            const int c = wid * 2 + j;
            gload_lds16(XB + (long)(brow + rA[j]) * K_DIM + kofs, &lds_a[buf][c * 512]);
            gload_lds16(WB + (long)(bcol + rA[j]) * K_DIM + kofs, &lds_b[buf][c * 512]);
        }
    };

    float4v acc[4][4] = {};

    stage(0, 0);
    __syncthreads();  // drains vmcnt(0): buf0 ready

    for (int kt = 0; kt < NT; ++kt) {
        const int cur = kt & 1;
        if (kt + 1 < NT) stage(cur ^ 1, kt + 1);  // loads fly across the phase

        const unsigned short* pa = &lds_a[cur][(wr * 4) * 512 + lane * 8];
        const unsigned short* pb = &lds_b[cur][(wc * 4) * 512 + lane * 8];
        short8 af[4], bfr[4];
#pragma unroll
        for (int i = 0; i < 4; ++i) {
            af[i]  = *(const short8*)(pa + i * 512);
            bfr[i] = *(const short8*)(pb + i * 512);
        }

#pragma unroll
        for (int mi = 0; mi < 4; ++mi)
#pragma unroll
            for (int ni = 0; ni < 4; ++ni)
                acc[mi][ni] = __builtin_amdgcn_mfma_f32_16x16x32_bf16(
                    af[mi], bfr[ni], acc[mi][ni], 0, 0, 0);

        __syncthreads();  // drains vmcnt(0)+lgkmcnt: next buf ready, cur reads done
    }

    // epilogue: D layout col = lane&15, row = (lane>>4)*4 + r
#pragma unroll
    for (int ni = 0; ni < 4; ++ni) {
        const int col = bcol + wc * 64 + ni * 16 + (lane & 15);
        const float bias = Bv[col];
#pragma unroll
        for (int mi = 0; mi < 4; ++mi) {
            const int row0 = brow + wr * 64 + mi * 16 + (lane >> 4) * 4;
#pragma unroll
            for (int r = 0; r < 4; ++r)
                O[(long)(row0 + r) * N_DIM + col] = acc[mi][ni][r] + bias;
        }
    }
}

// ---------------- round-1 fused kernel: fallback if ws too small ----------------
__global__ __launch_bounds__(256, 2)
void gemm_fused(const float* __restrict__ X, const float* __restrict__ W,
                const float* __restrict__ Bv, float* __restrict__ O) {
    __shared__ __align__(16) unsigned short lds_a[2][BM * LDS_STRIDE];
    __shared__ __align__(16) unsigned short lds_b[2][BN * LDS_STRIDE];

    const int tid  = threadIdx.x;
    const int lane = tid & 63;
    const int wid  = tid >> 6;
    const int wr   = wid >> 1;
    const int wc   = wid & 1;
    const int brow = blockIdx.y * BM;
    const int bcol = blockIdx.x * BN;
    const int srow  = tid >> 1;
    const int shalf = (tid & 1) * 16;

    const float* gA = X + (long)(brow + srow) * K_DIM + shalf;
    const float* gB = W + (long)(bcol + srow) * K_DIM + shalf;

    float4v ra[4], rb[4];
    auto load_regs = [&](int kt) {
        const float* pa = gA + kt * BK;
        const float* pb = gB + kt * BK;
#pragma unroll
        for (int j = 0; j < 4; ++j) ra[j] = *(const float4v*)(pa + j * 4);
#pragma unroll
        for (int j = 0; j < 4; ++j) rb[j] = *(const float4v*)(pb + j * 4);
    };
    auto write_lds = [&](int buf) {
        unsigned short* da = &lds_a[buf][srow * LDS_STRIDE + shalf];
        unsigned short* db = &lds_b[buf][srow * LDS_STRIDE + shalf];
        short8 va0, va1, vb0, vb1;
#pragma unroll
        for (int e = 0; e < 4; ++e) {
            va0[e] = (short)f2bf(ra[0][e]); va0[e+4] = (short)f2bf(ra[1][e]);
            va1[e] = (short)f2bf(ra[2][e]); va1[e+4] = (short)f2bf(ra[3][e]);
            vb0[e] = (short)f2bf(rb[0][e]); vb0[e+4] = (short)f2bf(rb[1][e]);
            vb1[e] = (short)f2bf(rb[2][e]); vb1[e+4] = (short)f2bf(rb[3][e]);
        }
        *(short8*)(da) = va0; *(short8*)(da + 8) = va1;
        *(short8*)(db) = vb0; *(short8*)(db + 8) = vb1;
    };

    float4v acc[4][4] = {};
    load_regs(0);
    write_lds(0);
    load_regs(1);
    __syncthreads();

    for (int kt = 0; kt < NT; ++kt) {
        const int cur = kt & 1;
        if (kt + 1 < NT) write_lds(cur ^ 1);
        if (kt + 2 < NT) load_regs(kt + 2);
        const unsigned short* ba =
            &lds_a[cur][(wr * 64 + (lane & 15)) * LDS_STRIDE + (lane >> 4) * 8];
        const unsigned short* bb =
            &lds_b[cur][(wc * 64 + (lane & 15)) * LDS_STRIDE + (lane >> 4) * 8];
        short8 af[4], bfr[4];
#pragma unroll
        for (int i = 0; i < 4; ++i) {
            af[i]  = *(const short8*)(ba + i * 16 * LDS_STRIDE);
            bfr[i] = *(const short8*)(bb + i * 16 * LDS_STRIDE);
        }
#pragma unroll
        for (int mi = 0; mi < 4; ++mi)
#pragma unroll
            for (int ni = 0; ni < 4; ++ni)
                acc[mi][ni] = __builtin_amdgcn_mfma_f32_16x16x32_bf16(
                    af[mi], bfr[ni], acc[mi][ni], 0, 0, 0);
        __syncthreads();
    }
#pragma unroll
    for (int ni = 0; ni < 4; ++ni) {
        const int col = bcol + wc * 64 + ni * 16 + (lane & 15);
        const float bias = Bv[col];
#pragma unroll
        for (int mi = 0; mi < 4; ++mi) {
            const int row0 = brow + wr * 64 + mi * 16 + (lane >> 4) * 4;
#pragma unroll
            for (int r = 0; r < 4; ++r)
                O[(long)(row0 + r) * N_DIM + col] = acc[mi][ni][r] + bias;
        }
    }
}

extern "C" void kernel_launch(void* const* d_in, const int* in_sizes, int n_in,
                              void* d_out, int out_size, void* d_ws, size_t ws_size,
                              hipStream_t stream) {
    const float* X  = (const float*)d_in[0];
    const float* W  = (const float*)d_in[1];
    const float* Bv = (const float*)d_in[2];
    float* O        = (float*)d_out;

    const size_t need = 2ull * M_DIM * K_DIM * sizeof(unsigned short);  // 64 MB
    if (ws_size >= need) {
        unsigned short* XB = (unsigned short*)d_ws;
        unsigned short* WB = XB + (size_t)M_DIM * K_DIM;
        hipLaunchKernelGGL(cvt_fp32_bf16, dim3(2048), dim3(256), 0, stream, X, W, XB, WB);
        dim3 grid(N_DIM / BN, M_DIM / BM);
        hipLaunchKernelGGL(gemm_bf16, grid, dim3(256), 0, stream, XB, WB, Bv, O);
    } else {
        dim3 grid(N_DIM / BN, M_DIM / BM);
        hipLaunchKernelGGL(gemm_fused, grid, dim3(256), 0, stream, X, W, Bv, O);
    }
}

// Round 3
// 151.699 us; speedup vs baseline: 1.9069x; 1.9069x over previous
//
#include <hip/hip_runtime.h>
#include <hip/hip_bf16.h>

#define M_DIM 4096
#define N_DIM 4096
#define K_DIM 4096
#define BM 256
#define BN 256
#define BK 64
#define NTILES (K_DIM / BK)   // 64

typedef __attribute__((ext_vector_type(8))) short short8;
typedef __attribute__((ext_vector_type(4))) float float4v;

__device__ __forceinline__ unsigned short f2bf(float f) {
    return __builtin_bit_cast(unsigned short, __float2bfloat16(f));
}

__device__ __forceinline__ void gload_lds16(const unsigned short* gsrc, unsigned short* lds) {
    __builtin_amdgcn_global_load_lds(
        (const __attribute__((address_space(1))) unsigned int*)gsrc,
        (__attribute__((address_space(3))) unsigned int*)lds,
        16, 0, 0);
}

// compiler fence + raw barrier (no vmcnt drain — we count vmcnt manually)
#define BAR() do { asm volatile("" ::: "memory"); __builtin_amdgcn_s_barrier(); \
                   asm volatile("" ::: "memory"); } while (0)

// 16-MFMA quadrant: compile-time acc offsets (rule #20: no runtime indexing)
#define MFMA_Q(AR, BR, MO, NO)                                                   \
  do {                                                                           \
    __builtin_amdgcn_s_setprio(1);                                               \
    _Pragma("unroll") for (int mf = 0; mf < 4; ++mf)                             \
      _Pragma("unroll") for (int nf = 0; nf < 2; ++nf)                           \
        _Pragma("unroll") for (int kk = 0; kk < 2; ++kk)                         \
          acc[(MO) + mf][(NO) + nf] = __builtin_amdgcn_mfma_f32_16x16x32_bf16(   \
              AR[mf][kk], BR[nf][kk], acc[(MO) + mf][(NO) + nf], 0, 0, 0);       \
    __builtin_amdgcn_s_setprio(0);                                               \
  } while (0)

// ---------------- fp32 -> bf16 conversion pass ----------------
__global__ __launch_bounds__(256)
void cvt_fp32_bf16(const float* __restrict__ X, const float* __restrict__ W,
                   unsigned short* __restrict__ XB, unsigned short* __restrict__ WB) {
    const long per_mat = (long)M_DIM * K_DIM / 8;
    const long total   = 2 * per_mat;
    for (long u = (long)blockIdx.x * blockDim.x + threadIdx.x; u < total;
         u += (long)gridDim.x * blockDim.x) {
        const float* src;
        unsigned short* dst;
        long v;
        if (u < per_mat) { src = X; dst = XB; v = u; }
        else             { src = W; dst = WB; v = u - per_mat; }
        float4v a = *(const float4v*)(src + v * 8);
        float4v b = *(const float4v*)(src + v * 8 + 4);
        short8 o;
#pragma unroll
        for (int e = 0; e < 4; ++e) {
            o[e]     = (short)f2bf(a[e]);
            o[e + 4] = (short)f2bf(b[e]);
        }
        *(short8*)(dst + v * 8) = o;
    }
}

// ---------------- 256x256 8-phase bf16 GEMM ----------------
// LDS: 8 regions x 16KB = 128KB. Region idx = mat*4 + half*2 + buf.
// Region layout: [128 rows][64 cols] bf16, st_16x32 swizzle (byte ^= ((byte>>9)&1)<<5).
// Staged by gload_lds (linear dest) from pre-swizzled global source; read with same XOR.
__global__ __launch_bounds__(512, 2)
void gemm_8ph(const unsigned short* __restrict__ XB, const unsigned short* __restrict__ WB,
              const float* __restrict__ Bv, float* __restrict__ O) {
    extern __shared__ unsigned short lds[];

    const int tid  = threadIdx.x;
    const int lane = tid & 63;
    const int wid  = tid >> 6;
    const int wm   = wid >> 2;   // 0..1 (M half)
    const int wn   = wid & 3;    // 0..3 (N quarter)

    // bijective XCD swizzle (nwg=256, %8==0)
    const int wg   = (blockIdx.x & 7) * 32 + (blockIdx.x >> 3);
    const int brow = (wg >> 4) * BM;
    const int bcol = (wg & 15) * BN;

    // --- staging source pre-swizzle: lds byte p -> unswizzled q -> (row, col)
    int rr[2], cc[2];
#pragma unroll
    for (int rho = 0; rho < 2; ++rho) {
        int p = rho * 8192 + tid * 16;
        int q = p ^ (((p >> 9) & 1) << 5);
        rr[rho] = q >> 7;            // row 0..127 within half-region
        cc[rho] = (q & 127) >> 1;    // col 0..63 (bf16)
    }

    // one 8KB sub-block stage: single gload_lds (64 lanes x 16B per wave)
    auto STAGE1 = [&](int mat, int half, int rho, int buf, int t) {
        const unsigned short* gbase = (mat == 0)
            ? XB + (long)(brow + half * 128) * K_DIM
            : WB + (long)(bcol + half * 128) * K_DIM;
        unsigned short* reg = lds + (mat * 4 + half * 2 + buf) * 8192;
        gload_lds16(gbase + (long)rr[rho] * K_DIM + t * 64 + cc[rho],
                    reg + rho * 4096 + wid * 512);
    };

    // --- fragment read addressing (shorts). byte = row*128 + (kk*64 + (l>>4)*16),
    // swizzle xor reduces to per-thread constant ((lane>>2)&1)<<5 on the col byte.
    const int xor5 = ((lane >> 2) & 1) << 5;
    int acol[2];
#pragma unroll
    for (int kk = 0; kk < 2; ++kk)
        acol[kk] = ((kk * 64 + (lane >> 4) * 16) ^ xor5) >> 1;
    const int arow = (lane & 15) * 64;

    auto LDA = [&](short8 (&dst)[4][2], int buf, int rho) {
        const unsigned short* base =
            lds + (wm * 2 + buf) * 8192 + rho * 4096 + arow;
#pragma unroll
        for (int mf = 0; mf < 4; ++mf)
#pragma unroll
            for (int kk = 0; kk < 2; ++kk)
                dst[mf][kk] = *(const short8*)(base + mf * 1024 + acol[kk]);
    };
    auto LDB = [&](short8 (&dst)[2][2], int buf, int nh) {
        const unsigned short* base =
            lds + (4 + (wn >> 1) * 2 + buf) * 8192 + (wn & 1) * 4096 + nh * 2048 + arow;
#pragma unroll
        for (int nf = 0; nf < 2; ++nf)
#pragma unroll
            for (int kk = 0; kk < 2; ++kk)
                dst[nf][kk] = *(const short8*)(base + nf * 1024 + acol[kk]);
    };

    float4v acc[8][4] = {};
    short8 a0[4][2], a1[4][2], b0[2][2], b1[2][2];

    // ---- prologue: tile0 fully (8 sub-blocks) + tile1's A + B-rho0 (6) ----
    STAGE1(0, 0, 0, 0, 0); STAGE1(0, 1, 0, 0, 0);
    STAGE1(0, 0, 1, 0, 0); STAGE1(0, 1, 1, 0, 0);
    STAGE1(1, 0, 0, 0, 0); STAGE1(1, 1, 0, 0, 0);
    STAGE1(1, 0, 1, 0, 0); STAGE1(1, 1, 1, 0, 0);
    STAGE1(0, 0, 0, 1, 1); STAGE1(0, 1, 0, 1, 1);
    STAGE1(0, 0, 1, 1, 1); STAGE1(0, 1, 1, 1, 1);
    STAGE1(1, 0, 0, 1, 1); STAGE1(1, 1, 0, 1, 1);
    asm volatile("s_waitcnt vmcnt(6)" ::: "memory");  // tile0's 8 landed
    BAR();

    // ---- main loop: 2 tiles / iteration, 8 phases ----
    auto do_tile = [&](int buf, int t) {
        // P1: read A-rho0 + B-lo; stage B-rho1 of t+1 (other buffer)
        LDA(a0, buf, 0);
        LDB(b0, buf, 0);
        if (t + 1 < NTILES) { STAGE1(1, 0, 1, buf ^ 1, t + 1); STAGE1(1, 1, 1, buf ^ 1, t + 1); }
        BAR();
        MFMA_Q(a0, b0, 0, 0);
        BAR();
        // P2: read A-rho1; stage A-rho0 of t+2 (this buffer; rho0 reads done at P1)
        LDA(a1, buf, 1);
        if (t + 2 < NTILES) { STAGE1(0, 0, 0, buf, t + 2); STAGE1(0, 1, 0, buf, t + 2); }
        BAR();
        MFMA_Q(a1, b0, 4, 0);
        BAR();
        // P3: read B-hi; stage A-rho1 of t+2 (rho1 reads done at P2)
        LDB(b1, buf, 1);
        if (t + 2 < NTILES) { STAGE1(0, 0, 1, buf, t + 2); STAGE1(0, 1, 1, buf, t + 2); }
        BAR();
        MFMA_Q(a1, b1, 4, 2);
        BAR();
        // P4: all-register MFMA; stage B-rho0 of t+2 (B reads done at P3); counted vmcnt
        if (t + 2 < NTILES) { STAGE1(1, 0, 0, buf, t + 2); STAGE1(1, 1, 0, buf, t + 2); }
        BAR();
        MFMA_Q(a0, b1, 0, 2);
        if (t + 2 < NTILES) {
            asm volatile("s_waitcnt vmcnt(6)" ::: "memory");   // tile t+1 fully landed
        } else if (t + 1 < NTILES) {
            asm volatile("s_waitcnt vmcnt(0)" ::: "memory");   // tail drain
        }
        BAR();
    };

    for (int it = 0; it < NTILES / 2; ++it) {
        do_tile(0, 2 * it);
        do_tile(1, 2 * it + 1);
    }

    // ---- epilogue: bias + store (D: col = lane&15, row = (lane>>4)*4 + r) ----
#pragma unroll
    for (int nf = 0; nf < 4; ++nf) {
        const int col = bcol + wn * 64 + nf * 16 + (lane & 15);
        const float bias = Bv[col];
#pragma unroll
        for (int mf = 0; mf < 8; ++mf) {
            const int row0 = brow + wm * 128 + mf * 16 + (lane >> 4) * 4;
#pragma unroll
            for (int r = 0; r < 4; ++r)
                O[(long)(row0 + r) * N_DIM + col] = acc[mf][nf][r] + bias;
        }
    }
}

extern "C" void kernel_launch(void* const* d_in, const int* in_sizes, int n_in,
                              void* d_out, int out_size, void* d_ws, size_t ws_size,
                              hipStream_t stream) {
    const float* X  = (const float*)d_in[0];
    const float* W  = (const float*)d_in[1];
    const float* Bv = (const float*)d_in[2];
    float* O        = (float*)d_out;

    unsigned short* XB = (unsigned short*)d_ws;
    unsigned short* WB = XB + (size_t)M_DIM * K_DIM;

    hipFuncSetAttribute((const void*)gemm_8ph,
                        hipFuncAttributeMaxDynamicSharedMemorySize, 131072);

    hipLaunchKernelGGL(cvt_fp32_bf16, dim3(2048), dim3(256), 0, stream, X, W, XB, WB);
    hipLaunchKernelGGL(gemm_8ph, dim3((M_DIM / BM) * (N_DIM / BN)), dim3(512), 131072,
                       stream, XB, WB, Bv, O);
}